// Round 8
// baseline (267.190 us; speedup 1.0000x reference)
//
#include <hip/hip_runtime.h>
#include <cstdint>
#include <cstddef>

typedef unsigned short u16;
typedef __bf16 bf16x8 __attribute__((ext_vector_type(8)));
typedef float f32x4 __attribute__((ext_vector_type(4)));
typedef unsigned int u32x4 __attribute__((ext_vector_type(4)));

// SCALE and pair-bias are pre-divided by ln2 so softmax can use exp2 directly.
#define SCALE_QK_LOG2 0.25509904f   // 32^-0.5 / ln(2)
#define INV_LN2 1.4426950408889634f

__device__ __forceinline__ u16 f2bf(float f){ return __builtin_bit_cast(u16, (__bf16)f); }
__device__ __forceinline__ float bf2f(u16 u){ unsigned v = ((unsigned)u)<<16; return __builtin_bit_cast(float, v); }
__device__ __forceinline__ bf16x8 ldfrag_g(const u16* p){
  return __builtin_bit_cast(bf16x8, *reinterpret_cast<const u32x4*>(p));
}
// async global->LDS, 16B per lane; lds base must be wave-uniform
__device__ __forceinline__ void gload16(const u16* g, u16* lds){
  __builtin_amdgcn_global_load_lds((const __attribute__((address_space(1))) unsigned int*)g,
                                   (__attribute__((address_space(3))) unsigned int*)lds, 16, 0, 0);
}

// ---------------- K0: f32 -> bf16 convert (msa) ----------------
__global__ __launch_bounds__(256) void k_cvt(const float* __restrict__ src,
                                             u16* __restrict__ dst, int n4){
  int stride = gridDim.x * blockDim.x;
  for (int idx = blockIdx.x*blockDim.x + threadIdx.x; idx < n4; idx += stride){
    float4 v = reinterpret_cast<const float4*>(src)[idx];
    ushort4 o;
    o.x = f2bf(v.x); o.y = f2bf(v.y); o.z = f2bf(v.z); o.w = f2bf(v.w);
    reinterpret_cast<ushort4*>(dst)[idx] = o;
  }
}

// ---------------- K0b: convert Wqkv (192 blocks) + Wout (64 blocks) ----------------
__global__ __launch_bounds__(256) void k_cvt2(const float* __restrict__ a, u16* __restrict__ da,
                                              const float* __restrict__ b, u16* __restrict__ db){
  int bid = blockIdx.x;
  if (bid < 192){
    int idx = bid*256 + threadIdx.x;
    float4 v = reinterpret_cast<const float4*>(a)[idx];
    ushort4 o; o.x=f2bf(v.x); o.y=f2bf(v.y); o.z=f2bf(v.z); o.w=f2bf(v.w);
    reinterpret_cast<ushort4*>(da)[idx] = o;
  } else {
    int idx = (bid-192)*256 + threadIdx.x;
    float4 v = reinterpret_cast<const float4*>(b)[idx];
    ushort4 o; o.x=f2bf(v.x); o.y=f2bf(v.y); o.z=f2bf(v.z); o.w=f2bf(v.w);
    reinterpret_cast<ushort4*>(db)[idx] = o;
  }
}

// ---------------- K1: pair bias + mask -> biasT[h][m][n] bf16, pre-scaled by 1/ln2 ----------------
__global__ __launch_bounds__(256) void k_pair_bias(const float* __restrict__ pair,
        const int* __restrict__ mask, const float* __restrict__ Wpb,
        const float* __restrict__ bpb, u16* __restrict__ bT){
  __shared__ float wsm[8][128];
  __shared__ float bsm[8];
  int tid = threadIdx.x;
  for (int i = tid; i < 1024; i += 256) wsm[i>>7][i&127] = Wpb[i];
  if (tid < 8) bsm[tid] = bpb[tid];
  __syncthreads();
  int g = tid>>4, l = tid&15;
  int row = blockIdx.x*16 + g;             // flat n*256 + m
  const float4* p = reinterpret_cast<const float4*>(pair + (size_t)row*128);
  float4 a0 = p[l];
  float4 a1 = p[l+16];
  int c0 = 4*l, c1 = 64 + 4*l;
  float acc[8];
#pragma unroll
  for (int hh=0; hh<8; hh++){
    acc[hh] = a0.x*wsm[hh][c0] + a0.y*wsm[hh][c0+1] + a0.z*wsm[hh][c0+2] + a0.w*wsm[hh][c0+3]
            + a1.x*wsm[hh][c1] + a1.y*wsm[hh][c1+1] + a1.z*wsm[hh][c1+2] + a1.w*wsm[hh][c1+3];
  }
#pragma unroll
  for (int hh=0; hh<8; hh++){
    float v = acc[hh];
    v += __shfl_xor(v,1); v += __shfl_xor(v,2); v += __shfl_xor(v,4); v += __shfl_xor(v,8);
    acc[hh] = v;
  }
  if (l == 0){
    float mb = (mask[row] == 0) ? -1e9f : 0.0f;
    int n = row>>8, m = row&255;
#pragma unroll
    for (int hh=0; hh<8; hh++)
      bT[hh*65536 + m*256 + n] = f2bf((acc[hh] + bsm[hh] + mb) * INV_LN2);
  }
}

// ---------------- K2: QKV GEMM (32768x768x256); q,k -> qkv[t][h][m][dh]; v -> vT[h][s][dh][key] ----------------
__global__ __launch_bounds__(256, 3) void k_qkv(const u16* __restrict__ A,
                                                const u16* __restrict__ B,
                                                const float* __restrict__ bq,
                                                u16* __restrict__ qkv,
                                                u16* __restrict__ vTg){
  __shared__ __align__(16) u16 Al[128*64];
  __shared__ __align__(16) u16 Bl[128*64];
  const int tid = threadIdx.x;
  const int w = tid>>6, l = tid&63;
  const int wm = w>>1, wn = w&1;
  const int m0 = blockIdx.y*128, n0 = blockIdx.x*128;
  const int lr = l&15, lg = l>>4;
  f32x4 acc[4][4] = {};
  for (int kt=0; kt<4; ++kt){
    const int k0 = kt*64;
    __syncthreads();
#pragma unroll
    for (int j=0;j<4;j++){
      int ch = w*256 + j*64 + l;          // chunk id 0..1023
      int r = ch>>3, sl = ch&7;
      gload16(A + (size_t)(m0+r)*256 + k0 + ((sl^(r&7))*8), Al + (size_t)(w*256 + j*64)*8);
      gload16(B + (size_t)(n0+r)*256 + k0 + ((sl^(r&7))*8), Bl + (size_t)(w*256 + j*64)*8);
    }
    __syncthreads();
#pragma unroll
    for (int ks=0; ks<2; ++ks){
      bf16x8 af[4], bfr[4];
#pragma unroll
      for (int t=0;t<4;t++){
        int ra = wm*64 + t*16 + lr;
        int sa = (ks*4 + lg) ^ (ra&7);
        af[t] = __builtin_bit_cast(bf16x8, *reinterpret_cast<const u32x4*>(&Al[ra*64 + sa*8]));
        int rb = wn*64 + t*16 + lr;
        int sb = (ks*4 + lg) ^ (rb&7);
        bfr[t] = __builtin_bit_cast(bf16x8, *reinterpret_cast<const u32x4*>(&Bl[rb*64 + sb*8]));
      }
#pragma unroll
      for (int tm=0;tm<4;tm++)
#pragma unroll
        for (int tn=0;tn<4;tn++)
          acc[tm][tn] = __builtin_amdgcn_mfma_f32_16x16x32_bf16(af[tm], bfr[tn], acc[tm][tn], 0,0,0);
    }
  }
#pragma unroll
  for (int tn=0;tn<4;tn++){
    int c = n0 + wn*64 + tn*16 + lr;       // 0..767
    int t3 = c>>8, hh = (c>>5)&7, dh = c&31;
    float bb = bq[c];
    if (t3 < 2){
      // q,k: [t][h][m][dh]
      u16* obase = qkv + (size_t)(t3*8+hh)*32768*32 + dh;
#pragma unroll
      for (int tm=0;tm<4;tm++)
#pragma unroll
        for (int rr=0;rr<4;rr++){
          int m = m0 + wm*64 + tm*16 + lg*4 + rr;
          obase[(size_t)m*32] = f2bf(acc[tm][tn][rr] + bb);
        }
    } else {
      // v: transposed [h][s][dh][key]
      u16* vbase = vTg + ((size_t)hh*128*32 + dh)*256;
#pragma unroll
      for (int tm=0;tm<4;tm++)
#pragma unroll
        for (int rr=0;rr<4;rr++){
          int m = m0 + wm*64 + tm*16 + lg*4 + rr;
          int s = m>>8, key = m&255;
          vbase[(size_t)s*32*256 + key] = f2bf(acc[tm][tn][rr] + bb);
        }
    }
  }
}

// ---------------- K3: attention; no barriers, V read from transposed global ----------------
__global__ __launch_bounds__(256, 3) void k_attn(const u16* __restrict__ qkv,
                                                 const u16* __restrict__ vTg,
                                                 const u16* __restrict__ bT,
                                                 u16* __restrict__ O){
  __shared__ __align__(16) u16 P[4][32*64];    // per-wave P chunk (64 keys), 16KB total
  const int h = blockIdx.x, s = blockIdx.y, z = blockIdx.z;
  const int tid = threadIdx.x;
  const int w = tid>>6, l = tid&63;
  const int lr = l&15, lg = l>>4;
  const int n0 = z*128 + 32*w;                 // this wave's first q-row
  const u16* qb = qkv + ((size_t)h*32768 + s*256)*32;
  const u16* kb = qkv + ((size_t)(8+h)*32768 + s*256)*32;
  const u16* vg = vTg + ((size_t)(h*128 + s)*32)*256;   // [dh][key]
  const u16* bb = bT + h*65536;

  bf16x8 qf[2];
#pragma unroll
  for (int t=0;t<2;t++)
    qf[t] = ldfrag_g(qb + (size_t)(n0 + t*16 + lr)*32 + lg*8);

  // ---- QK^T: all 256 keys into registers ----
  f32x4 sacc[2][16] = {};
#pragma unroll
  for (int kt=0; kt<4; ++kt){
    bf16x8 kf[4];
#pragma unroll
    for (int tn=0;tn<4;tn++)
      kf[tn] = ldfrag_g(kb + (size_t)(kt*64 + tn*16 + lr)*32 + lg*8);
#pragma unroll
    for (int t=0;t<2;t++)
#pragma unroll
      for (int tn=0;tn<4;tn++)
        sacc[t][kt*4+tn] = __builtin_amdgcn_mfma_f32_16x16x32_bf16(qf[t], kf[tn], sacc[t][kt*4+tn], 0,0,0);
  }

  // ---- scale (log2 domain) + bias ----
#pragma unroll
  for (int kt=0;kt<4;kt++){
#pragma unroll
    for (int t=0;t<2;t++)
#pragma unroll
      for (int tn=0;tn<4;tn++){
        ushort4 b4 = *reinterpret_cast<const ushort4*>(
            bb + (size_t)(kt*64 + tn*16 + lr)*256 + n0 + t*16 + lg*4);
        float bc[4] = { bf2f(b4.x), bf2f(b4.y), bf2f(b4.z), bf2f(b4.w) };
#pragma unroll
        for (int rr=0;rr<4;rr++)
          sacc[t][kt*4+tn][rr] = sacc[t][kt*4+tn][rr]*SCALE_QK_LOG2 + bc[rr];
      }
  }

  // ---- single-pass softmax: max/sum over all 16 reg-tiles + 16 lanes ----
  float inv_l[2][4];
#pragma unroll
  for (int t=0;t<2;t++){
#pragma unroll
    for (int rr=0;rr<4;rr++){
      float mx = sacc[t][0][rr];
#pragma unroll
      for (int j=1;j<16;j++) mx = fmaxf(mx, sacc[t][j][rr]);
      mx = fmaxf(mx, __shfl_xor(mx,1));
      mx = fmaxf(mx, __shfl_xor(mx,2));
      mx = fmaxf(mx, __shfl_xor(mx,4));
      mx = fmaxf(mx, __shfl_xor(mx,8));
      float ps = 0.f;
#pragma unroll
      for (int j=0;j<16;j++){
        float p = __builtin_amdgcn_exp2f(sacc[t][j][rr] - mx);
        sacc[t][j][rr] = p;
        ps += p;
      }
      ps += __shfl_xor(ps,1);
      ps += __shfl_xor(ps,2);
      ps += __shfl_xor(ps,4);
      ps += __shfl_xor(ps,8);
      inv_l[t][rr] = 1.0f / ps;
    }
  }

  // ---- PV: per 64-key chunk; P through per-wave LDS, V fragments from global (L2) ----
  f32x4 oacc[2][2] = {};
#pragma unroll
  for (int mt=0; mt<4; ++mt){
#pragma unroll
    for (int t=0;t<2;t++){
#pragma unroll
      for (int rr=0;rr<4;rr++){
        int row = t*16 + lg*4 + rr;          // 0..31
        int rb = row*64;
        int sx = row&7;
#pragma unroll
        for (int tn=0;tn<4;tn++){
          int col = tn*16 + lr;
          P[w][rb + (((col>>3)^sx)*8) + (col&7)] = f2bf(sacc[t][mt*4+tn][rr]);
        }
      }
    }
#pragma unroll
    for (int kk=0;kk<2;kk++){
      bf16x8 vf[2];
#pragma unroll
      for (int dt=0;dt<2;dt++){
        int c = dt*16 + lr;
        vf[dt] = ldfrag_g(vg + (size_t)c*256 + mt*64 + kk*32 + lg*8);
      }
#pragma unroll
      for (int t=0;t<2;t++){
        int ra = t*16 + lr;
        int sa = (kk*4 + lg) ^ (ra&7);
        bf16x8 pf = __builtin_bit_cast(bf16x8, *reinterpret_cast<const u32x4*>(&P[w][ra*64 + sa*8]));
        oacc[t][0] = __builtin_amdgcn_mfma_f32_16x16x32_bf16(pf, vf[0], oacc[t][0], 0,0,0);
        oacc[t][1] = __builtin_amdgcn_mfma_f32_16x16x32_bf16(pf, vf[1], oacc[t][1], 0,0,0);
      }
    }
  }
  // normalize + write O bf16 [s*256+n][h*32+dh]
#pragma unroll
  for (int t=0;t<2;t++){
#pragma unroll
    for (int rr=0;rr<4;rr++){
      int n = n0 + t*16 + lg*4 + rr;
      float inv = inv_l[t][rr];
      size_t rowb = (size_t)(s*256 + n)*256 + h*32;
#pragma unroll
      for (int dt=0;dt<2;dt++)
        O[rowb + dt*16 + lr] = f2bf(oacc[t][dt][rr]*inv);
    }
  }
}

// ---------------- K4: out-proj + bias + residual + LayerNorm ----------------
__global__ __launch_bounds__(256, 3) void k_out_ln(const u16* __restrict__ A,
        const u16* __restrict__ Wo, const float* __restrict__ bo,
        const float* __restrict__ msa, const float* __restrict__ gamma,
        const float* __restrict__ beta, float* __restrict__ out){
  __shared__ __align__(16) u16 Al[64*64];      // 8KB
  __shared__ __align__(16) u16 Wl[256*64];     // 32KB
  __shared__ float redS[64][4];
  __shared__ float redQ[64][4];
  const int tid = threadIdx.x;
  const int w = tid>>6, l = tid&63;
  const int lr = l&15, lg = l>>4;
  const int m0 = blockIdx.x*64;
  f32x4 acc[4][4] = {};
  for (int kt=0;kt<4;kt++){
    const int k0 = kt*64;
    __syncthreads();
#pragma unroll
    for (int j=0;j<2;j++){
      int ch = w*128 + j*64 + l;
      int r = ch>>3, sl = ch&7;
      gload16(A + (size_t)(m0+r)*256 + k0 + ((sl^(r&7))*8), Al + (size_t)(w*128 + j*64)*8);
    }
#pragma unroll
    for (int j=0;j<8;j++){
      int ch = w*512 + j*64 + l;
      int r = ch>>3, sl = ch&7;
      gload16(Wo + (size_t)r*256 + k0 + ((sl^(r&7))*8), Wl + (size_t)(w*512 + j*64)*8);
    }
    __syncthreads();
#pragma unroll
    for (int ks=0;ks<2;ks++){
      bf16x8 af[4], bfr[4];
#pragma unroll
      for (int t=0;t<4;t++){
        int ra = t*16 + lr;
        int sa = (ks*4+lg) ^ (ra&7);
        af[t] = __builtin_bit_cast(bf16x8, *reinterpret_cast<const u32x4*>(&Al[ra*64 + sa*8]));
        int rb = w*64 + t*16 + lr;
        int sb = (ks*4+lg) ^ (rb&7);
        bfr[t] = __builtin_bit_cast(bf16x8, *reinterpret_cast<const u32x4*>(&Wl[rb*64 + sb*8]));
      }
#pragma unroll
      for (int tm=0;tm<4;tm++)
#pragma unroll
        for (int tn=0;tn<4;tn++)
          acc[tm][tn] = __builtin_amdgcn_mfma_f32_16x16x32_bf16(af[tm], bfr[tn], acc[tm][tn], 0,0,0);
    }
  }
#pragma unroll
  for (int tn=0;tn<4;tn++){
    int c = w*64 + tn*16 + lr;
    float bc = bo[c];
#pragma unroll
    for (int tm=0;tm<4;tm++)
#pragma unroll
      for (int rr=0;rr<4;rr++){
        int m = m0 + tm*16 + lg*4 + rr;
        acc[tm][tn][rr] += bc + msa[(size_t)m*256 + c];
      }
  }
#pragma unroll
  for (int tm=0;tm<4;tm++){
#pragma unroll
    for (int rr=0;rr<4;rr++){
      float sS = 0.f, sQ = 0.f;
#pragma unroll
      for (int tn=0;tn<4;tn++){
        float v = acc[tm][tn][rr];
        sS += v; sQ += v*v;
      }
      sS += __shfl_xor(sS,1); sS += __shfl_xor(sS,2); sS += __shfl_xor(sS,4); sS += __shfl_xor(sS,8);
      sQ += __shfl_xor(sQ,1); sQ += __shfl_xor(sQ,2); sQ += __shfl_xor(sQ,4); sQ += __shfl_xor(sQ,8);
      if (lr == 0){
        int row = tm*16 + lg*4 + rr;
        redS[row][w] = sS;
        redQ[row][w] = sQ;
      }
    }
  }
  __syncthreads();
#pragma unroll
  for (int tm=0;tm<4;tm++){
#pragma unroll
    for (int rr=0;rr<4;rr++){
      int row = tm*16 + lg*4 + rr;
      float S = redS[row][0]+redS[row][1]+redS[row][2]+redS[row][3];
      float Q = redQ[row][0]+redQ[row][1]+redQ[row][2]+redQ[row][3];
      float mu = S * (1.0f/256.0f);
      float var = Q * (1.0f/256.0f) - mu*mu;
      float inv = rsqrtf(var + 1e-5f);
      int m = m0 + row;
#pragma unroll
      for (int tn=0;tn<4;tn++){
        int c = w*64 + tn*16 + lr;
        out[(size_t)m*256 + c] = (acc[tm][tn][rr]-mu)*inv*gamma[c] + beta[c];
      }
    }
  }
}

extern "C" void kernel_launch(void* const* d_in, const int* in_sizes, int n_in,
                              void* d_out, int out_size, void* d_ws, size_t ws_size,
                              hipStream_t stream) {
  const float* msa  = (const float*)d_in[0];
  const float* pair = (const float*)d_in[1];
  const int*   mask = (const int*)d_in[2];
  const float* Wqkv = (const float*)d_in[3];
  const float* bqkv = (const float*)d_in[4];
  const float* Wout = (const float*)d_in[5];
  const float* bout = (const float*)d_in[6];
  const float* Wpb  = (const float*)d_in[7];
  const float* bpb  = (const float*)d_in[8];
  const float* gamma= (const float*)d_in[9];
  const float* beta = (const float*)d_in[10];
  float* out = (float*)d_out;

  char* ws = (char*)d_ws;
  u16*   msa_bf  = (u16*)(ws);                 // 16,777,216 B
  u16*   wqkv_bf = (u16*)(ws + 16777216);      //    393,216 B
  u16*   wout_bf = (u16*)(ws + 17170432);      //    131,072 B
  u16*   biasT   = (u16*)(ws + 17301504);      //  1,048,576 B  bf16 [h][m][n], pre-scaled 1/ln2
  u16*   qkvb    = (u16*)(ws + 18350080);      // 33,554,432 B  q,k only
  u16*   vTg     = (u16*)(ws + 51904512);      // 16,777,216 B  v transposed [h][s][dh][key]
  u16*   Ob      = (u16*)(ws + 68681728);      // 16,777,216 B  (total 85,458,944 B)

  k_cvt<<<4096, 256, 0, stream>>>(msa, msa_bf, 8388608/4);
  k_cvt2<<<256, 256, 0, stream>>>(Wqkv, wqkv_bf, Wout, wout_bf);
  k_pair_bias<<<4096, 256, 0, stream>>>(pair, mask, Wpb, bpb, biasT);
  k_qkv<<<dim3(6,256), 256, 0, stream>>>(msa_bf, wqkv_bf, bqkv, qkvb, vTg);
  k_attn<<<dim3(8,128,2), 256, 0, stream>>>(qkvb, vTg, biasT, Ob);
  k_out_ln<<<512, 256, 0, stream>>>(Ob, wout_bf, bout, msa, gamma, beta, out);
}

// Round 9
// 249.896 us; speedup vs baseline: 1.0692x; 1.0692x over previous
//
#include <hip/hip_runtime.h>
#include <cstdint>
#include <cstddef>

typedef unsigned short u16;
typedef __bf16 bf16x8 __attribute__((ext_vector_type(8)));
typedef float f32x4 __attribute__((ext_vector_type(4)));
typedef unsigned int u32x4 __attribute__((ext_vector_type(4)));

// SCALE and pair-bias are pre-divided by ln2 so softmax can use exp2 directly.
#define SCALE_QK_LOG2 0.25509904f   // 32^-0.5 / ln(2)
#define INV_LN2 1.4426950408889634f

__device__ __forceinline__ u16 f2bf(float f){ return __builtin_bit_cast(u16, (__bf16)f); }
__device__ __forceinline__ float bf2f(u16 u){ unsigned v = ((unsigned)u)<<16; return __builtin_bit_cast(float, v); }
__device__ __forceinline__ bf16x8 ldfrag_g(const u16* p){
  return __builtin_bit_cast(bf16x8, *reinterpret_cast<const u32x4*>(p));
}
// async global->LDS, 16B per lane; lds base must be wave-uniform
__device__ __forceinline__ void gload16(const u16* g, u16* lds){
  __builtin_amdgcn_global_load_lds((const __attribute__((address_space(1))) unsigned int*)g,
                                   (__attribute__((address_space(3))) unsigned int*)lds, 16, 0, 0);
}

// ---------------- K-pre: pair_bias (blocks 0..4095) + weight converts (4096..4351) ----------------
__global__ __launch_bounds__(256) void k_pre(const float* __restrict__ pair,
        const int* __restrict__ mask, const float* __restrict__ Wpb,
        const float* __restrict__ bpb, u16* __restrict__ bT,
        const float* __restrict__ Wqkv, u16* __restrict__ wqkv_bf,
        const float* __restrict__ Wout, u16* __restrict__ wout_bf){
  int bid = blockIdx.x;
  int tid = threadIdx.x;
  if (bid >= 4096){
    int cb = bid - 4096;
    if (cb < 192){
      int idx = cb*256 + tid;
      float4 v = reinterpret_cast<const float4*>(Wqkv)[idx];
      ushort4 o; o.x=f2bf(v.x); o.y=f2bf(v.y); o.z=f2bf(v.z); o.w=f2bf(v.w);
      reinterpret_cast<ushort4*>(wqkv_bf)[idx] = o;
    } else {
      int idx = (cb-192)*256 + tid;
      float4 v = reinterpret_cast<const float4*>(Wout)[idx];
      ushort4 o; o.x=f2bf(v.x); o.y=f2bf(v.y); o.z=f2bf(v.z); o.w=f2bf(v.w);
      reinterpret_cast<ushort4*>(wout_bf)[idx] = o;
    }
    return;
  }
  __shared__ float wsm[8][128];
  __shared__ float bsm[8];
  for (int i = tid; i < 1024; i += 256) wsm[i>>7][i&127] = Wpb[i];
  if (tid < 8) bsm[tid] = bpb[tid];
  __syncthreads();
  int g = tid>>4, l = tid&15;
  int row = bid*16 + g;             // flat n*256 + m
  const float4* p = reinterpret_cast<const float4*>(pair + (size_t)row*128);
  float4 a0 = p[l];
  float4 a1 = p[l+16];
  int c0 = 4*l, c1 = 64 + 4*l;
  float acc[8];
#pragma unroll
  for (int hh=0; hh<8; hh++){
    acc[hh] = a0.x*wsm[hh][c0] + a0.y*wsm[hh][c0+1] + a0.z*wsm[hh][c0+2] + a0.w*wsm[hh][c0+3]
            + a1.x*wsm[hh][c1] + a1.y*wsm[hh][c1+1] + a1.z*wsm[hh][c1+2] + a1.w*wsm[hh][c1+3];
  }
#pragma unroll
  for (int hh=0; hh<8; hh++){
    float v = acc[hh];
    v += __shfl_xor(v,1); v += __shfl_xor(v,2); v += __shfl_xor(v,4); v += __shfl_xor(v,8);
    acc[hh] = v;
  }
  if (l == 0){
    float mb = (mask[row] == 0) ? -1e9f : 0.0f;
    int n = row>>8, m = row&255;
#pragma unroll
    for (int hh=0; hh<8; hh++)
      bT[hh*65536 + m*256 + n] = f2bf((acc[hh] + bsm[hh] + mb) * INV_LN2);
  }
}

// ---------------- K2: QKV GEMM (32768x768x256); A = msa f32 converted in staging ----------------
__global__ __launch_bounds__(256, 3) void k_qkv(const float* __restrict__ Amsa,
                                                const u16* __restrict__ B,
                                                const float* __restrict__ bq,
                                                u16* __restrict__ qkv){
  __shared__ __align__(16) u16 Al[128*64];
  __shared__ __align__(16) u16 Bl[128*64];
  const int tid = threadIdx.x;
  const int w = tid>>6, l = tid&63;
  const int wm = w>>1, wn = w&1;
  const int m0 = blockIdx.y*128, n0 = blockIdx.x*128;
  const int lr = l&15, lg = l>>4;
  f32x4 acc[4][4] = {};
  for (int kt=0; kt<4; ++kt){
    const int k0 = kt*64;
    __syncthreads();
#pragma unroll
    for (int j=0;j<4;j++){
      int ch = tid + 256*j;               // chunk id 0..1023
      int r = ch>>3, sl = ch&7;
      // A: f32 global (natural layout) -> convert -> swizzled LDS slot
      const float* src = Amsa + (size_t)(m0+r)*256 + k0 + sl*8;
      float4 x0 = reinterpret_cast<const float4*>(src)[0];
      float4 x1 = reinterpret_cast<const float4*>(src)[1];
      ushort4 lo, hi;
      lo.x=f2bf(x0.x); lo.y=f2bf(x0.y); lo.z=f2bf(x0.z); lo.w=f2bf(x0.w);
      hi.x=f2bf(x1.x); hi.y=f2bf(x1.y); hi.z=f2bf(x1.z); hi.w=f2bf(x1.w);
      u16* dst = &Al[r*64 + ((sl^(r&7))*8)];
      reinterpret_cast<ushort4*>(dst)[0] = lo;
      reinterpret_cast<ushort4*>(dst)[1] = hi;
      // B: bf16, pre-swizzled global source + linear LDS dest (wave-uniform base)
      gload16(B + (size_t)(n0+r)*256 + k0 + ((sl^(r&7))*8), Bl + (size_t)(w*64 + 256*j)*8);
    }
    __syncthreads();
#pragma unroll
    for (int ks=0; ks<2; ++ks){
      bf16x8 af[4], bfr[4];
#pragma unroll
      for (int t=0;t<4;t++){
        int ra = wm*64 + t*16 + lr;
        int sa = (ks*4 + lg) ^ (ra&7);
        af[t] = __builtin_bit_cast(bf16x8, *reinterpret_cast<const u32x4*>(&Al[ra*64 + sa*8]));
        int rb = wn*64 + t*16 + lr;
        int sb = (ks*4 + lg) ^ (rb&7);
        bfr[t] = __builtin_bit_cast(bf16x8, *reinterpret_cast<const u32x4*>(&Bl[rb*64 + sb*8]));
      }
#pragma unroll
      for (int tm=0;tm<4;tm++)
#pragma unroll
        for (int tn=0;tn<4;tn++)
          acc[tm][tn] = __builtin_amdgcn_mfma_f32_16x16x32_bf16(af[tm], bfr[tn], acc[tm][tn], 0,0,0);
    }
  }
#pragma unroll
  for (int tn=0;tn<4;tn++){
    int c = n0 + wn*64 + tn*16 + lr;       // 0..767
    int t3 = c>>8, hh = (c>>5)&7, dh = c&31;
    float bb = bq[c];
    u16* obase = qkv + (size_t)(t3*8+hh)*32768*32 + dh;
#pragma unroll
    for (int tm=0;tm<4;tm++){
#pragma unroll
      for (int rr=0;rr<4;rr++){
        int m = m0 + wm*64 + tm*16 + lg*4 + rr;
        obase[(size_t)m*32] = f2bf(acc[tm][tn][rr] + bb);
      }
    }
  }
}

// ---------------- K3: attention; 8 waves per (h,s), V staged once, single-pass softmax ----------------
__global__ __launch_bounds__(512, 2) void k_attn(const u16* __restrict__ qkv,
                                                 const u16* __restrict__ bT,
                                                 u16* __restrict__ O){
  __shared__ __align__(16) u16 vT[32*256];     // [dh][m] swizzled, 16KB
  __shared__ __align__(16) u16 P[8][32*64];    // per-wave P chunk, 32KB
  const int h = blockIdx.x, s = blockIdx.y;
  const int tid = threadIdx.x;
  const int w = tid>>6, l = tid&63;
  const int lr = l&15, lg = l>>4;
  const int n0 = 32*w;                         // this wave's first q-row
  const u16* qb = qkv + ((size_t)h*32768 + s*256)*32;
  const u16* kb = qkv + ((size_t)(8+h)*32768 + s*256)*32;
  const u16* vb = qkv + ((size_t)(16+h)*32768 + s*256)*32;
  const u16* bb = bT + h*65536;

  // stage V transposed: vT[dh][m]
#pragma unroll
  for (int i=0;i<2;i++){
    int flat4 = tid + 512*i;                 // 1024 chunks of 8 elems
    int m = flat4>>2, d0 = (flat4&3)*8;
    u32x4 d = *reinterpret_cast<const u32x4*>(vb + (size_t)m*32 + d0);
    u16 tmp[8];
    *reinterpret_cast<u32x4*>(tmp) = d;
#pragma unroll
    for (int j=0;j<8;j++){
      int dh = d0 + j;
      vT[dh*256 + (((m>>3)^(dh&7))*8) + (m&7)] = tmp[j];
    }
  }
  __syncthreads();

  bf16x8 qf[2];
#pragma unroll
  for (int t=0;t<2;t++)
    qf[t] = ldfrag_g(qb + (size_t)(n0 + t*16 + lr)*32 + lg*8);

  // ---- QK^T: all 256 keys into registers ----
  f32x4 sacc[2][16] = {};
#pragma unroll
  for (int kt=0; kt<4; ++kt){
    bf16x8 kf[4];
#pragma unroll
    for (int tn=0;tn<4;tn++)
      kf[tn] = ldfrag_g(kb + (size_t)(kt*64 + tn*16 + lr)*32 + lg*8);
#pragma unroll
    for (int t=0;t<2;t++)
#pragma unroll
      for (int tn=0;tn<4;tn++)
        sacc[t][kt*4+tn] = __builtin_amdgcn_mfma_f32_16x16x32_bf16(qf[t], kf[tn], sacc[t][kt*4+tn], 0,0,0);
  }

  // ---- scale (log2 domain) + bias ----
#pragma unroll
  for (int kt=0;kt<4;kt++){
#pragma unroll
    for (int t=0;t<2;t++)
#pragma unroll
      for (int tn=0;tn<4;tn++){
        ushort4 b4 = *reinterpret_cast<const ushort4*>(
            bb + (size_t)(kt*64 + tn*16 + lr)*256 + n0 + t*16 + lg*4);
        float bc[4] = { bf2f(b4.x), bf2f(b4.y), bf2f(b4.z), bf2f(b4.w) };
#pragma unroll
        for (int rr=0;rr<4;rr++)
          sacc[t][kt*4+tn][rr] = sacc[t][kt*4+tn][rr]*SCALE_QK_LOG2 + bc[rr];
      }
  }

  // ---- single-pass softmax ----
  float inv_l[2][4];
#pragma unroll
  for (int t=0;t<2;t++){
#pragma unroll
    for (int rr=0;rr<4;rr++){
      float mx = sacc[t][0][rr];
#pragma unroll
      for (int j=1;j<16;j++) mx = fmaxf(mx, sacc[t][j][rr]);
      mx = fmaxf(mx, __shfl_xor(mx,1));
      mx = fmaxf(mx, __shfl_xor(mx,2));
      mx = fmaxf(mx, __shfl_xor(mx,4));
      mx = fmaxf(mx, __shfl_xor(mx,8));
      float ps = 0.f;
#pragma unroll
      for (int j=0;j<16;j++){
        float p = __builtin_amdgcn_exp2f(sacc[t][j][rr] - mx);
        sacc[t][j][rr] = p;
        ps += p;
      }
      ps += __shfl_xor(ps,1);
      ps += __shfl_xor(ps,2);
      ps += __shfl_xor(ps,4);
      ps += __shfl_xor(ps,8);
      inv_l[t][rr] = 1.0f / ps;
    }
  }

  // ---- PV: per 64-key chunk through per-wave LDS ----
  f32x4 oacc[2][2] = {};
#pragma unroll
  for (int mt=0; mt<4; ++mt){
#pragma unroll
    for (int t=0;t<2;t++){
#pragma unroll
      for (int rr=0;rr<4;rr++){
        int row = t*16 + lg*4 + rr;          // 0..31
        int rb = row*64;
        int sx = row&7;
#pragma unroll
        for (int tn=0;tn<4;tn++){
          int col = tn*16 + lr;
          P[w][rb + (((col>>3)^sx)*8) + (col&7)] = f2bf(sacc[t][mt*4+tn][rr]);
        }
      }
    }
#pragma unroll
    for (int kk=0;kk<2;kk++){
      bf16x8 vf[2];
#pragma unroll
      for (int dt=0;dt<2;dt++){
        int c = dt*16 + lr;
        int slot = (mt*8 + kk*4 + lg) ^ (c&7);
        vf[dt] = __builtin_bit_cast(bf16x8, *reinterpret_cast<const u32x4*>(&vT[c*256 + slot*8]));
      }
#pragma unroll
      for (int t=0;t<2;t++){
        int ra = t*16 + lr;
        int sa = (kk*4 + lg) ^ (ra&7);
        bf16x8 pf = __builtin_bit_cast(bf16x8, *reinterpret_cast<const u32x4*>(&P[w][ra*64 + sa*8]));
        oacc[t][0] = __builtin_amdgcn_mfma_f32_16x16x32_bf16(pf, vf[0], oacc[t][0], 0,0,0);
        oacc[t][1] = __builtin_amdgcn_mfma_f32_16x16x32_bf16(pf, vf[1], oacc[t][1], 0,0,0);
      }
    }
  }
  // normalize + write O bf16 [s*256+n][h*32+dh]
#pragma unroll
  for (int t=0;t<2;t++){
#pragma unroll
    for (int rr=0;rr<4;rr++){
      int n = n0 + t*16 + lg*4 + rr;
      float inv = inv_l[t][rr];
      size_t rowb = (size_t)(s*256 + n)*256 + h*32;
#pragma unroll
      for (int dt=0;dt<2;dt++)
        O[rowb + dt*16 + lr] = f2bf(oacc[t][dt][rr]*inv);
    }
  }
}

// ---------------- K4: out-proj + bias + residual + LayerNorm ----------------
__global__ __launch_bounds__(256, 3) void k_out_ln(const u16* __restrict__ A,
        const u16* __restrict__ Wo, const float* __restrict__ bo,
        const float* __restrict__ msa, const float* __restrict__ gamma,
        const float* __restrict__ beta, float* __restrict__ out){
  __shared__ __align__(16) u16 Al[64*64];      // 8KB
  __shared__ __align__(16) u16 Wl[256*64];     // 32KB
  __shared__ float redS[64][4];
  __shared__ float redQ[64][4];
  const int tid = threadIdx.x;
  const int w = tid>>6, l = tid&63;
  const int lr = l&15, lg = l>>4;
  const int m0 = blockIdx.x*64;
  f32x4 acc[4][4] = {};
  for (int kt=0;kt<4;kt++){
    const int k0 = kt*64;
    __syncthreads();
#pragma unroll
    for (int j=0;j<2;j++){
      int ch = w*128 + j*64 + l;
      int r = ch>>3, sl = ch&7;
      gload16(A + (size_t)(m0+r)*256 + k0 + ((sl^(r&7))*8), Al + (size_t)(w*128 + j*64)*8);
    }
#pragma unroll
    for (int j=0;j<8;j++){
      int ch = w*512 + j*64 + l;
      int r = ch>>3, sl = ch&7;
      gload16(Wo + (size_t)r*256 + k0 + ((sl^(r&7))*8), Wl + (size_t)(w*512 + j*64)*8);
    }
    __syncthreads();
#pragma unroll
    for (int ks=0;ks<2;ks++){
      bf16x8 af[4], bfr[4];
#pragma unroll
      for (int t=0;t<4;t++){
        int ra = t*16 + lr;
        int sa = (ks*4+lg) ^ (ra&7);
        af[t] = __builtin_bit_cast(bf16x8, *reinterpret_cast<const u32x4*>(&Al[ra*64 + sa*8]));
        int rb = w*64 + t*16 + lr;
        int sb = (ks*4+lg) ^ (rb&7);
        bfr[t] = __builtin_bit_cast(bf16x8, *reinterpret_cast<const u32x4*>(&Wl[rb*64 + sb*8]));
      }
#pragma unroll
      for (int tm=0;tm<4;tm++)
#pragma unroll
        for (int tn=0;tn<4;tn++)
          acc[tm][tn] = __builtin_amdgcn_mfma_f32_16x16x32_bf16(af[tm], bfr[tn], acc[tm][tn], 0,0,0);
    }
  }
#pragma unroll
  for (int tn=0;tn<4;tn++){
    int c = w*64 + tn*16 + lr;
    float bc = bo[c];
#pragma unroll
    for (int tm=0;tm<4;tm++)
#pragma unroll
      for (int rr=0;rr<4;rr++){
        int m = m0 + tm*16 + lg*4 + rr;
        acc[tm][tn][rr] += bc + msa[(size_t)m*256 + c];
      }
  }
#pragma unroll
  for (int tm=0;tm<4;tm++){
#pragma unroll
    for (int rr=0;rr<4;rr++){
      float sS = 0.f, sQ = 0.f;
#pragma unroll
      for (int tn=0;tn<4;tn++){
        float v = acc[tm][tn][rr];
        sS += v; sQ += v*v;
      }
      sS += __shfl_xor(sS,1); sS += __shfl_xor(sS,2); sS += __shfl_xor(sS,4); sS += __shfl_xor(sS,8);
      sQ += __shfl_xor(sQ,1); sQ += __shfl_xor(sQ,2); sQ += __shfl_xor(sQ,4); sQ += __shfl_xor(sQ,8);
      if (lr == 0){
        int row = tm*16 + lg*4 + rr;
        redS[row][w] = sS;
        redQ[row][w] = sQ;
      }
    }
  }
  __syncthreads();
#pragma unroll
  for (int tm=0;tm<4;tm++){
#pragma unroll
    for (int rr=0;rr<4;rr++){
      int row = tm*16 + lg*4 + rr;
      float S = redS[row][0]+redS[row][1]+redS[row][2]+redS[row][3];
      float Q = redQ[row][0]+redQ[row][1]+redQ[row][2]+redQ[row][3];
      float mu = S * (1.0f/256.0f);
      float var = Q * (1.0f/256.0f) - mu*mu;
      float inv = rsqrtf(var + 1e-5f);
      int m = m0 + row;
#pragma unroll
      for (int tn=0;tn<4;tn++){
        int c = w*64 + tn*16 + lr;
        out[(size_t)m*256 + c] = (acc[tm][tn][rr]-mu)*inv*gamma[c] + beta[c];
      }
    }
  }
}

extern "C" void kernel_launch(void* const* d_in, const int* in_sizes, int n_in,
                              void* d_out, int out_size, void* d_ws, size_t ws_size,
                              hipStream_t stream) {
  const float* msa  = (const float*)d_in[0];
  const float* pair = (const float*)d_in[1];
  const int*   mask = (const int*)d_in[2];
  const float* Wqkv = (const float*)d_in[3];
  const float* bqkv = (const float*)d_in[4];
  const float* Wout = (const float*)d_in[5];
  const float* bout = (const float*)d_in[6];
  const float* Wpb  = (const float*)d_in[7];
  const float* bpb  = (const float*)d_in[8];
  const float* gamma= (const float*)d_in[9];
  const float* beta = (const float*)d_in[10];
  float* out = (float*)d_out;

  char* ws = (char*)d_ws;
  u16*   wqkv_bf = (u16*)(ws);                 //    393,216 B
  u16*   wout_bf = (u16*)(ws + 393216);        //    131,072 B
  u16*   biasT   = (u16*)(ws + 524288);        //  1,048,576 B  bf16 [h][m][n], pre-scaled 1/ln2
  u16*   qkvb    = (u16*)(ws + 1572864);       // 50,331,648 B  [t][h][m][dh]
  u16*   Ob      = (u16*)(ws + 51904512);      // 16,777,216 B  (total 68,681,728 B)

  k_pre<<<4352, 256, 0, stream>>>(pair, mask, Wpb, bpb, biasT, Wqkv, wqkv_bf, Wout, wout_bf);
  k_qkv<<<dim3(6,256), 256, 0, stream>>>(msa, wqkv_bf, bqkv, qkvb);
  k_attn<<<dim3(8,128), 512, 0, stream>>>(qkvb, biasT, Ob);
  k_out_ln<<<512, 256, 0, stream>>>(Ob, wout_bf, bout, msa, gamma, beta, out);
}

// Round 11
// 239.405 us; speedup vs baseline: 1.1161x; 1.0438x over previous
//
#include <hip/hip_runtime.h>
#include <cstdint>
#include <cstddef>

typedef unsigned short u16;
typedef __bf16 bf16x8 __attribute__((ext_vector_type(8)));
typedef float f32x4 __attribute__((ext_vector_type(4)));
typedef unsigned int u32x4 __attribute__((ext_vector_type(4)));

// SCALE and pair-bias are pre-divided by ln2 so softmax can use exp2 directly.
#define SCALE_QK_LOG2 0.25509904f   // 32^-0.5 / ln(2)
#define INV_LN2 1.4426950408889634f

__device__ __forceinline__ u16 f2bf(float f){ return __builtin_bit_cast(u16, (__bf16)f); }
__device__ __forceinline__ float bf2f(u16 u){ unsigned v = ((unsigned)u)<<16; return __builtin_bit_cast(float, v); }
__device__ __forceinline__ bf16x8 ldfrag_g(const u16* p){
  return __builtin_bit_cast(bf16x8, *reinterpret_cast<const u32x4*>(p));
}
// async global->LDS, 16B per lane; lds base must be wave-uniform
__device__ __forceinline__ void gload16(const u16* g, u16* lds){
  __builtin_amdgcn_global_load_lds((const __attribute__((address_space(1))) unsigned int*)g,
                                   (__attribute__((address_space(3))) unsigned int*)lds, 16, 0, 0);
}

// ---------------- K-pre: pair_bias (blocks 0..4095) + weight converts (4096..4351) ----------------
__global__ __launch_bounds__(256) void k_pre(const float* __restrict__ pair,
        const int* __restrict__ mask, const float* __restrict__ Wpb,
        const float* __restrict__ bpb, u16* __restrict__ bT,
        const float* __restrict__ Wqkv, u16* __restrict__ wqkv_bf,
        const float* __restrict__ Wout, u16* __restrict__ wout_bf){
  int bid = blockIdx.x;
  int tid = threadIdx.x;
  if (bid >= 4096){
    int cb = bid - 4096;
    if (cb < 192){
      int idx = cb*256 + tid;
      float4 v = reinterpret_cast<const float4*>(Wqkv)[idx];
      ushort4 o; o.x=f2bf(v.x); o.y=f2bf(v.y); o.z=f2bf(v.z); o.w=f2bf(v.w);
      reinterpret_cast<ushort4*>(wqkv_bf)[idx] = o;
    } else {
      int idx = (cb-192)*256 + tid;
      float4 v = reinterpret_cast<const float4*>(Wout)[idx];
      ushort4 o; o.x=f2bf(v.x); o.y=f2bf(v.y); o.z=f2bf(v.z); o.w=f2bf(v.w);
      reinterpret_cast<ushort4*>(wout_bf)[idx] = o;
    }
    return;
  }
  __shared__ float wsm[8][128];
  __shared__ float bsm[8];
  for (int i = tid; i < 1024; i += 256) wsm[i>>7][i&127] = Wpb[i];
  if (tid < 8) bsm[tid] = bpb[tid];
  __syncthreads();
  int g = tid>>4, l = tid&15;
  int row = bid*16 + g;             // flat n*256 + m
  const float4* p = reinterpret_cast<const float4*>(pair + (size_t)row*128);
  float4 a0 = p[l];
  float4 a1 = p[l+16];
  int c0 = 4*l, c1 = 64 + 4*l;
  float acc[8];
#pragma unroll
  for (int hh=0; hh<8; hh++){
    acc[hh] = a0.x*wsm[hh][c0] + a0.y*wsm[hh][c0+1] + a0.z*wsm[hh][c0+2] + a0.w*wsm[hh][c0+3]
            + a1.x*wsm[hh][c1] + a1.y*wsm[hh][c1+1] + a1.z*wsm[hh][c1+2] + a1.w*wsm[hh][c1+3];
  }
#pragma unroll
  for (int hh=0; hh<8; hh++){
    float v = acc[hh];
    v += __shfl_xor(v,1); v += __shfl_xor(v,2); v += __shfl_xor(v,4); v += __shfl_xor(v,8);
    acc[hh] = v;
  }
  if (l == 0){
    float mb = (mask[row] == 0) ? -1e9f : 0.0f;
    int n = row>>8, m = row&255;
#pragma unroll
    for (int hh=0; hh<8; hh++)
      bT[hh*65536 + m*256 + n] = f2bf((acc[hh] + bsm[hh] + mb) * INV_LN2);
  }
}

// ---------------- K2: QKV GEMM (32768x768x256); A = msa f32 converted in staging ----------------
__global__ __launch_bounds__(256, 3) void k_qkv(const float* __restrict__ Amsa,
                                                const u16* __restrict__ B,
                                                const float* __restrict__ bq,
                                                u16* __restrict__ qkv){
  __shared__ __align__(16) u16 Al[128*64];
  __shared__ __align__(16) u16 Bl[128*64];
  const int tid = threadIdx.x;
  const int w = tid>>6, l = tid&63;
  const int wm = w>>1, wn = w&1;
  const int m0 = blockIdx.y*128, n0 = blockIdx.x*128;
  const int lr = l&15, lg = l>>4;
  f32x4 acc[4][4] = {};
  for (int kt=0; kt<4; ++kt){
    const int k0 = kt*64;
    __syncthreads();
#pragma unroll
    for (int j=0;j<4;j++){
      int ch = tid + 256*j;               // chunk id 0..1023
      int r = ch>>3, sl = ch&7;
      const float* src = Amsa + (size_t)(m0+r)*256 + k0 + sl*8;
      float4 x0 = reinterpret_cast<const float4*>(src)[0];
      float4 x1 = reinterpret_cast<const float4*>(src)[1];
      ushort4 lo, hi;
      lo.x=f2bf(x0.x); lo.y=f2bf(x0.y); lo.z=f2bf(x0.z); lo.w=f2bf(x0.w);
      hi.x=f2bf(x1.x); hi.y=f2bf(x1.y); hi.z=f2bf(x1.z); hi.w=f2bf(x1.w);
      u16* dst = &Al[r*64 + ((sl^(r&7))*8)];
      reinterpret_cast<ushort4*>(dst)[0] = lo;
      reinterpret_cast<ushort4*>(dst)[1] = hi;
      gload16(B + (size_t)(n0+r)*256 + k0 + ((sl^(r&7))*8), Bl + (size_t)(w*64 + 256*j)*8);
    }
    __syncthreads();
#pragma unroll
    for (int ks=0; ks<2; ++ks){
      bf16x8 af[4], bfr[4];
#pragma unroll
      for (int t=0;t<4;t++){
        int ra = wm*64 + t*16 + lr;
        int sa = (ks*4 + lg) ^ (ra&7);
        af[t] = __builtin_bit_cast(bf16x8, *reinterpret_cast<const u32x4*>(&Al[ra*64 + sa*8]));
        int rb = wn*64 + t*16 + lr;
        int sb = (ks*4 + lg) ^ (rb&7);
        bfr[t] = __builtin_bit_cast(bf16x8, *reinterpret_cast<const u32x4*>(&Bl[rb*64 + sb*8]));
      }
#pragma unroll
      for (int tm=0;tm<4;tm++)
#pragma unroll
        for (int tn=0;tn<4;tn++)
          acc[tm][tn] = __builtin_amdgcn_mfma_f32_16x16x32_bf16(af[tm], bfr[tn], acc[tm][tn], 0,0,0);
    }
  }
#pragma unroll
  for (int tn=0;tn<4;tn++){
    int c = n0 + wn*64 + tn*16 + lr;       // 0..767
    int t3 = c>>8, hh = (c>>5)&7, dh = c&31;
    float bb = bq[c];
    u16* obase = qkv + (size_t)(t3*8+hh)*32768*32 + dh;
#pragma unroll
    for (int tm=0;tm<4;tm++){
#pragma unroll
      for (int rr=0;rr<4;rr++){
        int m = m0 + wm*64 + tm*16 + lg*4 + rr;
        obase[(size_t)m*32] = f2bf(acc[tm][tn][rr] + bb);
      }
    }
  }
}

// ---------------- K3: attention; single-pass softmax over all 256 keys in registers ----------------
__global__ __launch_bounds__(256, 2) void k_attn(const u16* __restrict__ qkv,
                                                 const u16* __restrict__ bT,
                                                 u16* __restrict__ O){
  __shared__ __align__(16) u16 vT[32*256];     // [dh][m] swizzled, 16KB
  __shared__ __align__(16) u16 P[4][32*64];    // per-wave P chunk (64 keys), 16KB
  const int h = blockIdx.x, s = blockIdx.y, z = blockIdx.z;
  const int tid = threadIdx.x;
  const int w = tid>>6, l = tid&63;
  const int lr = l&15, lg = l>>4;
  const int n0 = z*128 + 32*w;                 // this wave's first q-row
  const u16* qb = qkv + ((size_t)h*32768 + s*256)*32;
  const u16* kb = qkv + ((size_t)(8+h)*32768 + s*256)*32;
  const u16* vb = qkv + ((size_t)(16+h)*32768 + s*256)*32;
  const u16* bb = bT + h*65536;

  // stage V transposed: vT[dh][m]
#pragma unroll
  for (int i=0;i<4;i++){
    int flat4 = tid + 256*i;                 // 1024 chunks of 8 elems
    int m = flat4>>2, d0 = (flat4&3)*8;
    u32x4 d = *reinterpret_cast<const u32x4*>(vb + (size_t)m*32 + d0);
    u16 tmp[8];
    *reinterpret_cast<u32x4*>(tmp) = d;
#pragma unroll
    for (int j=0;j<8;j++){
      int dh = d0 + j;
      vT[dh*256 + (((m>>3)^(dh&7))*8) + (m&7)] = tmp[j];
    }
  }
  __syncthreads();

  bf16x8 qf[2];
#pragma unroll
  for (int t=0;t<2;t++)
    qf[t] = ldfrag_g(qb + (size_t)(n0 + t*16 + lr)*32 + lg*8);

  // ---- QK^T: all 256 keys into registers ----
  f32x4 sacc[2][16] = {};
#pragma unroll
  for (int kt=0; kt<4; ++kt){
    bf16x8 kf[4];
#pragma unroll
    for (int tn=0;tn<4;tn++)
      kf[tn] = ldfrag_g(kb + (size_t)(kt*64 + tn*16 + lr)*32 + lg*8);
#pragma unroll
    for (int t=0;t<2;t++)
#pragma unroll
      for (int tn=0;tn<4;tn++)
        sacc[t][kt*4+tn] = __builtin_amdgcn_mfma_f32_16x16x32_bf16(qf[t], kf[tn], sacc[t][kt*4+tn], 0,0,0);
  }

  // ---- scale (log2 domain) + bias ----
#pragma unroll
  for (int kt=0;kt<4;kt++){
#pragma unroll
    for (int t=0;t<2;t++)
#pragma unroll
      for (int tn=0;tn<4;tn++){
        ushort4 b4 = *reinterpret_cast<const ushort4*>(
            bb + (size_t)(kt*64 + tn*16 + lr)*256 + n0 + t*16 + lg*4);
        float bc[4] = { bf2f(b4.x), bf2f(b4.y), bf2f(b4.z), bf2f(b4.w) };
#pragma unroll
        for (int rr=0;rr<4;rr++)
          sacc[t][kt*4+tn][rr] = sacc[t][kt*4+tn][rr]*SCALE_QK_LOG2 + bc[rr];
      }
  }

  // ---- single-pass softmax: max/sum over all 16 reg-tiles + 16 lanes ----
  float inv_l[2][4];
#pragma unroll
  for (int t=0;t<2;t++){
#pragma unroll
    for (int rr=0;rr<4;rr++){
      float mx = sacc[t][0][rr];
#pragma unroll
      for (int j=1;j<16;j++) mx = fmaxf(mx, sacc[t][j][rr]);
      mx = fmaxf(mx, __shfl_xor(mx,1));
      mx = fmaxf(mx, __shfl_xor(mx,2));
      mx = fmaxf(mx, __shfl_xor(mx,4));
      mx = fmaxf(mx, __shfl_xor(mx,8));
      float ps = 0.f;
#pragma unroll
      for (int j=0;j<16;j++){
        float p = __builtin_amdgcn_exp2f(sacc[t][j][rr] - mx);
        sacc[t][j][rr] = p;
        ps += p;
      }
      ps += __shfl_xor(ps,1);
      ps += __shfl_xor(ps,2);
      ps += __shfl_xor(ps,4);
      ps += __shfl_xor(ps,8);
      inv_l[t][rr] = 1.0f / ps;
    }
  }

  // ---- PV: per 64-key chunk through per-wave LDS (P transpose), no rescale needed ----
  f32x4 oacc[2][2] = {};
#pragma unroll
  for (int mt=0; mt<4; ++mt){
#pragma unroll
    for (int t=0;t<2;t++){
#pragma unroll
      for (int rr=0;rr<4;rr++){
        int row = t*16 + lg*4 + rr;          // 0..31
        int rb = row*64;
        int sx = row&7;
#pragma unroll
        for (int tn=0;tn<4;tn++){
          int col = tn*16 + lr;
          P[w][rb + (((col>>3)^sx)*8) + (col&7)] = f2bf(sacc[t][mt*4+tn][rr]);
        }
      }
    }
#pragma unroll
    for (int kk=0;kk<2;kk++){
      bf16x8 vf[2];
#pragma unroll
      for (int dt=0;dt<2;dt++){
        int c = dt*16 + lr;
        int slot = (mt*8 + kk*4 + lg) ^ (c&7);
        vf[dt] = __builtin_bit_cast(bf16x8, *reinterpret_cast<const u32x4*>(&vT[c*256 + slot*8]));
      }
#pragma unroll
      for (int t=0;t<2;t++){
        int ra = t*16 + lr;
        int sa = (kk*4 + lg) ^ (ra&7);
        bf16x8 pf = __builtin_bit_cast(bf16x8, *reinterpret_cast<const u32x4*>(&P[w][ra*64 + sa*8]));
        oacc[t][0] = __builtin_amdgcn_mfma_f32_16x16x32_bf16(pf, vf[0], oacc[t][0], 0,0,0);
        oacc[t][1] = __builtin_amdgcn_mfma_f32_16x16x32_bf16(pf, vf[1], oacc[t][1], 0,0,0);
      }
    }
  }
  // normalize + write O bf16 [s*256+n][h*32+dh]
#pragma unroll
  for (int t=0;t<2;t++){
#pragma unroll
    for (int rr=0;rr<4;rr++){
      int n = n0 + t*16 + lg*4 + rr;
      float inv = inv_l[t][rr];
      size_t rowb = (size_t)(s*256 + n)*256 + h*32;
#pragma unroll
      for (int dt=0;dt<2;dt++)
        O[rowb + dt*16 + lr] = f2bf(oacc[t][dt][rr]*inv);
    }
  }
}

// ---------------- K4: out-proj + bias + residual + LayerNorm ----------------
__global__ __launch_bounds__(256, 3) void k_out_ln(const u16* __restrict__ A,
        const u16* __restrict__ Wo, const float* __restrict__ bo,
        const float* __restrict__ msa, const float* __restrict__ gamma,
        const float* __restrict__ beta, float* __restrict__ out){
  __shared__ __align__(16) u16 Al[64*64];      // 8KB
  __shared__ __align__(16) u16 Wl[256*64];     // 32KB
  __shared__ float redS[64][4];
  __shared__ float redQ[64][4];
  const int tid = threadIdx.x;
  const int w = tid>>6, l = tid&63;
  const int lr = l&15, lg = l>>4;
  const int m0 = blockIdx.x*64;
  f32x4 acc[4][4] = {};
  for (int kt=0;kt<4;kt++){
    const int k0 = kt*64;
    __syncthreads();
#pragma unroll
    for (int j=0;j<2;j++){
      int ch = w*128 + j*64 + l;
      int r = ch>>3, sl = ch&7;
      gload16(A + (size_t)(m0+r)*256 + k0 + ((sl^(r&7))*8), Al + (size_t)(w*128 + j*64)*8);
    }
#pragma unroll
    for (int j=0;j<8;j++){
      int ch = w*512 + j*64 + l;
      int r = ch>>3, sl = ch&7;
      gload16(Wo + (size_t)r*256 + k0 + ((sl^(r&7))*8), Wl + (size_t)(w*512 + j*64)*8);
    }
    __syncthreads();
#pragma unroll
    for (int ks=0;ks<2;ks++){
      bf16x8 af[4], bfr[4];
#pragma unroll
      for (int t=0;t<4;t++){
        int ra = t*16 + lr;
        int sa = (ks*4+lg) ^ (ra&7);
        af[t] = __builtin_bit_cast(bf16x8, *reinterpret_cast<const u32x4*>(&Al[ra*64 + sa*8]));
        int rb = w*64 + t*16 + lr;
        int sb = (ks*4+lg) ^ (rb&7);
        bfr[t] = __builtin_bit_cast(bf16x8, *reinterpret_cast<const u32x4*>(&Wl[rb*64 + sb*8]));
      }
#pragma unroll
      for (int tm=0;tm<4;tm++)
#pragma unroll
        for (int tn=0;tn<4;tn++)
          acc[tm][tn] = __builtin_amdgcn_mfma_f32_16x16x32_bf16(af[tm], bfr[tn], acc[tm][tn], 0,0,0);
    }
  }
#pragma unroll
  for (int tn=0;tn<4;tn++){
    int c = w*64 + tn*16 + lr;
    float bc = bo[c];
#pragma unroll
    for (int tm=0;tm<4;tm++)
#pragma unroll
      for (int rr=0;rr<4;rr++){
        int m = m0 + tm*16 + lg*4 + rr;
        acc[tm][tn][rr] += bc + msa[(size_t)m*256 + c];
      }
  }
#pragma unroll
  for (int tm=0;tm<4;tm++){
#pragma unroll
    for (int rr=0;rr<4;rr++){
      float sS = 0.f, sQ = 0.f;
#pragma unroll
      for (int tn=0;tn<4;tn++){
        float v = acc[tm][tn][rr];
        sS += v; sQ += v*v;
      }
      sS += __shfl_xor(sS,1); sS += __shfl_xor(sS,2); sS += __shfl_xor(sS,4); sS += __shfl_xor(sS,8);
      sQ += __shfl_xor(sQ,1); sQ += __shfl_xor(sQ,2); sQ += __shfl_xor(sQ,4); sQ += __shfl_xor(sQ,8);
      if (lr == 0){
        int row = tm*16 + lg*4 + rr;
        redS[row][w] = sS;
        redQ[row][w] = sQ;
      }
    }
  }
  __syncthreads();
#pragma unroll
  for (int tm=0;tm<4;tm++){
#pragma unroll
    for (int rr=0;rr<4;rr++){
      int row = tm*16 + lg*4 + rr;
      float S = redS[row][0]+redS[row][1]+redS[row][2]+redS[row][3];
      float Q = redQ[row][0]+redQ[row][1]+redQ[row][2]+redQ[row][3];
      float mu = S * (1.0f/256.0f);
      float var = Q * (1.0f/256.0f) - mu*mu;
      float inv = rsqrtf(var + 1e-5f);
      int m = m0 + row;
#pragma unroll
      for (int tn=0;tn<4;tn++){
        int c = w*64 + tn*16 + lr;
        out[(size_t)m*256 + c] = (acc[tm][tn][rr]-mu)*inv*gamma[c] + beta[c];
      }
    }
  }
}

extern "C" void kernel_launch(void* const* d_in, const int* in_sizes, int n_in,
                              void* d_out, int out_size, void* d_ws, size_t ws_size,
                              hipStream_t stream) {
  const float* msa  = (const float*)d_in[0];
  const float* pair = (const float*)d_in[1];
  const int*   mask = (const int*)d_in[2];
  const float* Wqkv = (const float*)d_in[3];
  const float* bqkv = (const float*)d_in[4];
  const float* Wout = (const float*)d_in[5];
  const float* bout = (const float*)d_in[6];
  const float* Wpb  = (const float*)d_in[7];
  const float* bpb  = (const float*)d_in[8];
  const float* gamma= (const float*)d_in[9];
  const float* beta = (const float*)d_in[10];
  float* out = (float*)d_out;

  char* ws = (char*)d_ws;
  u16*   wqkv_bf = (u16*)(ws);                 //    393,216 B
  u16*   wout_bf = (u16*)(ws + 393216);        //    131,072 B
  u16*   biasT   = (u16*)(ws + 524288);        //  1,048,576 B  bf16 [h][m][n], pre-scaled 1/ln2
  u16*   qkvb    = (u16*)(ws + 1572864);       // 50,331,648 B  [t][h][m][dh]
  u16*   Ob      = (u16*)(ws + 51904512);      // 16,777,216 B  (total 68,681,728 B)

  k_pre<<<4352, 256, 0, stream>>>(pair, mask, Wpb, bpb, biasT, Wqkv, wqkv_bf, Wout, wout_bf);
  k_qkv<<<dim3(6,256), 256, 0, stream>>>(msa, wqkv_bf, bqkv, qkvb);
  k_attn<<<dim3(8,128,2), 256, 0, stream>>>(qkvb, biasT, Ob);
  k_out_ln<<<512, 256, 0, stream>>>(Ob, wout_bf, bout, msa, gamma, beta, out);
}